// Round 1
// baseline (1532.440 us; speedup 1.0000x reference)
//
#include <hip/hip_runtime.h>
#include <hip/hip_bf16.h>
#include <math.h>

// Problem constants (AttentionPool): B=8, N=4096, C=1536, H=24, hd=64, R=8
#define Bb 8
#define Nn 4096
#define Cc 1536
#define Hh 24
#define HD 64
#define RR 8
#define MKV (Bb * Nn)        // 32768 rows for K/V GEMM
#define NKV (2 * Cc)         // 3072 cols (K and V fused)

typedef unsigned short u16;
typedef unsigned int u32;

typedef __attribute__((ext_vector_type(8))) short bf16x8;
typedef __attribute__((ext_vector_type(4))) float f32x4;

__device__ __forceinline__ u16 f32_to_bf16(float f) {
    union { float f; u32 u; } v; v.f = f;
    u32 r = v.u + 0x7fffu + ((v.u >> 16) & 1u);  // RNE
    return (u16)(r >> 16);
}
__device__ __forceinline__ float bflo(u32 p) {
    union { u32 u; float f; } v; v.u = p << 16; return v.f;
}
__device__ __forceinline__ float bfhi(u32 p) {
    union { u32 u; float f; } v; v.u = p & 0xffff0000u; return v.f;
}

// ---------------- cast f32 -> bf16, 4 elems/thread ----------------
__global__ __launch_bounds__(256)
void cast4_f32_bf16(const float4* __restrict__ src, u16* __restrict__ dst, int n4) {
    int i = blockIdx.x * blockDim.x + threadIdx.x;
    if (i < n4) {
        float4 v = src[i];
        ushort4 o;
        o.x = f32_to_bf16(v.x); o.y = f32_to_bf16(v.y);
        o.z = f32_to_bf16(v.z); o.w = f32_to_bf16(v.w);
        *(ushort4*)(dst + (size_t)i * 4) = o;
    }
}

// ---------------- gather first R tokens per batch, * SCALE, -> bf16 ----------------
__global__ __launch_bounds__(256)
void gather_q_kernel(const float* __restrict__ x, u16* __restrict__ xqp) {
    int i = blockIdx.x * blockDim.x + threadIdx.x;  // < 64*1536
    int m = i / Cc, c = i - m * Cc;
    int b = m >> 3, r = m & 7;
    xqp[i] = f32_to_bf16(x[((size_t)b * Nn + r) * Cc + c] * 0.125f);  // SCALE=hd^-0.5
}

// ---------------- m97-style GEMM: C[M,N] = A[M,K] * B[N,K]^T (+bias) ----------------
__device__ __forceinline__ void storeC(float* C, size_t i, float v) { C[i] = v; }
__device__ __forceinline__ void storeC(u16* C, size_t i, float v) { C[i] = f32_to_bf16(v); }

template <typename OutT>
__global__ __launch_bounds__(256)
void gemm_bt(const u16* __restrict__ A, const u16* __restrict__ B,
             OutT* __restrict__ C, const float* __restrict__ bias,
             int M, int N, int K, int M_valid)
{
    __shared__ u16 As[128 * 32];
    __shared__ u16 Bs[128 * 32];
    const int tid = threadIdx.x;
    const int m0 = blockIdx.y * 128;
    const int n0 = blockIdx.x * 128;
    const int wave = tid >> 6;
    const int lane = tid & 63;
    const int wm = (wave & 1) * 64;
    const int wn = (wave >> 1) * 64;
    const int fm = lane & 15;            // row within 16x16 frag
    const int ko = (lane >> 4) * 8;      // k offset within frag

    f32x4 acc[4][4] = {};

    // staging: 256 threads x 16B x 2 chunks = 8192B = 128x32 bf16 tile
    const int e0 = tid * 8;              // element offset, chunk 0
    const int e1 = tid * 8 + 2048;       // chunk 1
    const int r0 = e0 >> 5, c0 = e0 & 31;
    const int r1 = e1 >> 5, c1 = e1 & 31;
    const u16* Arow0 = A + (size_t)(m0 + r0) * K + c0;
    const u16* Arow1 = A + (size_t)(m0 + r1) * K + c1;
    const u16* Brow0 = B + (size_t)(n0 + r0) * K + c0;
    const u16* Brow1 = B + (size_t)(n0 + r1) * K + c1;

    for (int k0 = 0; k0 < K; k0 += 32) {
        __builtin_amdgcn_global_load_lds(
            (const __attribute__((address_space(1))) void*)(Arow0 + k0),
            (__attribute__((address_space(3))) void*)(As + e0), 16, 0, 0);
        __builtin_amdgcn_global_load_lds(
            (const __attribute__((address_space(1))) void*)(Arow1 + k0),
            (__attribute__((address_space(3))) void*)(As + e1), 16, 0, 0);
        __builtin_amdgcn_global_load_lds(
            (const __attribute__((address_space(1))) void*)(Brow0 + k0),
            (__attribute__((address_space(3))) void*)(Bs + e0), 16, 0, 0);
        __builtin_amdgcn_global_load_lds(
            (const __attribute__((address_space(1))) void*)(Brow1 + k0),
            (__attribute__((address_space(3))) void*)(Bs + e1), 16, 0, 0);
        __syncthreads();

        bf16x8 af[4], bfr[4];
        #pragma unroll
        for (int i = 0; i < 4; ++i)
            af[i] = *(const bf16x8*)&As[(wm + i * 16 + fm) * 32 + ko];
        #pragma unroll
        for (int j = 0; j < 4; ++j)
            bfr[j] = *(const bf16x8*)&Bs[(wn + j * 16 + fm) * 32 + ko];
        #pragma unroll
        for (int i = 0; i < 4; ++i)
            #pragma unroll
            for (int j = 0; j < 4; ++j)
                acc[i][j] = __builtin_amdgcn_mfma_f32_16x16x32_bf16(af[i], bfr[j], acc[i][j], 0, 0, 0);
        __syncthreads();
    }

    // C/D layout: col = lane&15, row = (lane>>4)*4 + reg  [guide m89, verified]
    const int col = lane & 15;
    const int rb = (lane >> 4) * 4;
    #pragma unroll
    for (int i = 0; i < 4; ++i) {
        #pragma unroll
        for (int j = 0; j < 4; ++j) {
            #pragma unroll
            for (int rg = 0; rg < 4; ++rg) {
                int m = m0 + wm + i * 16 + rb + rg;
                if (m < M_valid) {
                    int n = n0 + wn + j * 16 + col;
                    float v = acc[i][j][rg];
                    if (bias) v += bias[n];
                    storeC(C, (size_t)m * N + n, v);
                }
            }
        }
    }
}

// ---------------- attention: one workgroup per (b,h) ----------------
// kv: bf16 [MKV, 3072]; cols 0..1535 = K proj, 1536..3071 = V proj
// qout: f32 [128,1536] rows (b*8+r); scores scratch f32 [192][8][4096]
__global__ __launch_bounds__(256)
void attn_kernel(const float* __restrict__ qout, const u16* __restrict__ kv,
                 const int* __restrict__ mask, float* __restrict__ sc_ws,
                 u16* __restrict__ aob)
{
    const int bh = blockIdx.x;          // 0..191
    const int b = bh / Hh, h = bh - b * Hh;
    const int tid = threadIdx.x;
    __shared__ float qs[RR * HD];       // 2 KB
    __shared__ float red[256];
    __shared__ float mrow[RR], lrow[RR];
    float* sc = sc_ws + (size_t)bh * RR * Nn;

    // load q tile
    for (int i = tid; i < RR * HD; i += 256)
        qs[i] = qout[(size_t)(b * RR + (i >> 6)) * Cc + h * HD + (i & 63)];
    __syncthreads();

    // ---- phase 1: masked scores ----
    for (int j = tid; j < Nn; j += 256) {
        float s[RR] = {0, 0, 0, 0, 0, 0, 0, 0};
        const u16* krow = kv + (size_t)(b * Nn + j) * NKV + h * HD;
        for (int c = 0; c < 8; ++c) {
            uint4 kvec = *(const uint4*)(krow + c * 8);
            float kf0 = bflo(kvec.x), kf1 = bfhi(kvec.x);
            float kf2 = bflo(kvec.y), kf3 = bfhi(kvec.y);
            float kf4 = bflo(kvec.z), kf5 = bfhi(kvec.z);
            float kf6 = bflo(kvec.w), kf7 = bfhi(kvec.w);
            #pragma unroll
            for (int r = 0; r < RR; ++r) {
                const float4 qa = *(const float4*)&qs[r * HD + c * 8];
                const float4 qb = *(const float4*)&qs[r * HD + c * 8 + 4];
                s[r] += qa.x * kf0 + qa.y * kf1 + qa.z * kf2 + qa.w * kf3
                      + qb.x * kf4 + qb.y * kf5 + qb.z * kf6 + qb.w * kf7;
            }
        }
        #pragma unroll
        for (int r = 0; r < RR; ++r) {
            bool keep = (j < RR) ? (j == r)
                                 : (mask[(size_t)(b * RR + r) * (Nn - RR) + (j - RR)] != 0);
            sc[r * Nn + j] = keep ? s[r] : -INFINITY;
        }
    }
    __syncthreads();

    // ---- phase 2: softmax (max, exp, sum) ----
    {
        const int r = tid >> 5, g = tid & 31;
        float mx = -INFINITY;
        for (int i = 0; i < Nn / 32; ++i) mx = fmaxf(mx, sc[r * Nn + g + 32 * i]);
        red[tid] = mx;
        __syncthreads();
        if (tid < RR) {
            float m2 = -INFINITY;
            for (int i = 0; i < 32; ++i) m2 = fmaxf(m2, red[tid * 32 + i]);
            mrow[tid] = m2;
        }
        __syncthreads();
        const float m = mrow[r];
        float sum = 0.f;
        for (int i = 0; i < Nn / 32; ++i) {
            int idx = r * Nn + g + 32 * i;
            float e = __expf(sc[idx] - m);   // exp(-inf)=0 handles mask
            sc[idx] = e;
            sum += e;
        }
        red[tid] = sum;
        __syncthreads();
        if (tid < RR) {
            float l = 0.f;
            for (int i = 0; i < 32; ++i) l += red[tid * 32 + i];
            lrow[tid] = l;
        }
        __syncthreads();
    }

    // ---- phase 3: out[r,d] = sum_n P[r,n] * v[n,d] ----
    {
        const int r = tid >> 5;
        const int d = (tid & 31) * 2;
        const float linv = 1.0f / lrow[r];
        const float* pr = sc + r * Nn;
        const u16* vbase = kv + (size_t)b * Nn * NKV + Cc + h * HD + d;
        float a0 = 0.f, a1 = 0.f;
        #pragma unroll 4
        for (int n = 0; n < Nn; ++n) {
            float p = pr[n];
            u32 vv = *(const u32*)(vbase + (size_t)n * NKV);
            a0 += p * bflo(vv);
            a1 += p * bfhi(vv);
        }
        size_t o = (size_t)(b * RR + r) * Cc + h * HD + d;
        aob[o]     = f32_to_bf16(a0 * linv);
        aob[o + 1] = f32_to_bf16(a1 * linv);
    }
}

// ---------------- launch ----------------
extern "C" void kernel_launch(void* const* d_in, const int* in_sizes, int n_in,
                              void* d_out, int out_size, void* d_ws, size_t ws_size,
                              hipStream_t stream)
{
    const float* x    = (const float*)d_in[0];
    const int*   mask = (const int*)d_in[1];
    const float* Wq   = (const float*)d_in[2];
    const float* Wk   = (const float*)d_in[3];
    const float* Wv   = (const float*)d_in[4];
    const float* Wp   = (const float*)d_in[5];
    const float* bp   = (const float*)d_in[6];
    // d_in[7] = repeats (=8, hardcoded as RR)

    char* ws = (char*)d_ws;
    // workspace layout (bytes), ~322.5 MB total
    u16*   xb     = (u16*)(ws);                       // 100,663,296  x bf16 [32768,1536]
    u16*   wkvb   = (u16*)(ws + 100663296);           //   9,437,184  [Wk;Wv] bf16 [3072,1536]
    u16*   wqb    = (u16*)(ws + 110100480);           //   4,718,592  Wq bf16
    u16*   wpb    = (u16*)(ws + 114819072);           //   4,718,592  Wp bf16
    u16*   kvb    = (u16*)(ws + 119537664);           // 201,326,592  kv bf16 [32768,3072]
    u16*   xqp    = (u16*)(ws + 320864256);           //     393,216  q input padded [128,1536] bf16
    float* qout   = (float*)(ws + 321257472);         //     786,432  q proj f32 [128,1536]
    u16*   aob    = (u16*)(ws + 322043904);           //     393,216  attn out padded [128,1536] bf16
    float* scores = (float*)ws;                       // aliases xb (dead after GEMMs): 25 MB

    // casts (x: 12.58M quads; W: 589824 quads each)
    cast4_f32_bf16<<<49152, 256, 0, stream>>>((const float4*)x, xb, 12582912);
    cast4_f32_bf16<<<2304, 256, 0, stream>>>((const float4*)Wk, wkvb, 589824);
    cast4_f32_bf16<<<2304, 256, 0, stream>>>((const float4*)Wv, wkvb + 2359296, 589824);
    cast4_f32_bf16<<<2304, 256, 0, stream>>>((const float4*)Wq, wqb, 589824);
    cast4_f32_bf16<<<2304, 256, 0, stream>>>((const float4*)Wp, wpb, 589824);

    // zero pad rows of the two M=128-padded GEMM inputs
    hipMemsetAsync(xqp, 0, 128 * Cc * sizeof(u16), stream);
    hipMemsetAsync(aob, 0, 128 * Cc * sizeof(u16), stream);

    gather_q_kernel<<<384, 256, 0, stream>>>(x, xqp);

    // q projection: [128,1536] = xqp @ Wq^T   (scale already folded into xqp)
    gemm_bt<float><<<dim3(12, 1), 256, 0, stream>>>(xqp, wqb, qout, nullptr, 128, Cc, Cc, 128);

    // fused K+V projection: [32768,3072] = xb @ [Wk;Wv]^T
    gemm_bt<u16><<<dim3(NKV / 128, MKV / 128), 256, 0, stream>>>(xb, wkvb, kvb, nullptr,
                                                                 MKV, NKV, Cc, MKV);

    // attention (writes bf16 into aob rows 0..63)
    attn_kernel<<<192, 256, 0, stream>>>(qout, kvb, mask, scores, aob);

    // output projection: d_out[64,1536] = aob @ Wp^T + bp
    gemm_bt<float><<<dim3(12, 1), 256, 0, stream>>>(aob, wpb, (float*)d_out, bp, 128, Cc, Cc, 64);
}

// Round 2
// 1026.575 us; speedup vs baseline: 1.4928x; 1.4928x over previous
//
#include <hip/hip_runtime.h>
#include <hip/hip_bf16.h>
#include <math.h>

// Problem constants (AttentionPool): B=8, N=4096, C=1536, H=24, hd=64, R=8
#define Bb 8
#define Nn 4096
#define Cc 1536
#define Hh 24
#define HD 64
#define RR 8
#define MKV (Bb * Nn)        // 32768 rows for K/V GEMM
#define NKV (2 * Cc)         // 3072 cols (K and V fused)
#define NCHUNK 16            // key chunks for split attention
#define CK 256               // keys per chunk

typedef unsigned short u16;
typedef unsigned int u32;

typedef __attribute__((ext_vector_type(8))) short bf16x8;
typedef __attribute__((ext_vector_type(4))) float f32x4;

__device__ __forceinline__ u16 f32_to_bf16(float f) {
    union { float f; u32 u; } v; v.f = f;
    u32 r = v.u + 0x7fffu + ((v.u >> 16) & 1u);  // RNE
    return (u16)(r >> 16);
}
__device__ __forceinline__ float bflo(u32 p) {
    union { u32 u; float f; } v; v.u = p << 16; return v.f;
}
__device__ __forceinline__ float bfhi(u32 p) {
    union { u32 u; float f; } v; v.u = p & 0xffff0000u; return v.f;
}

// ---------------- cast f32 -> bf16, 4 elems/thread ----------------
__global__ __launch_bounds__(256)
void cast4_f32_bf16(const float4* __restrict__ src, u16* __restrict__ dst, int n4) {
    int i = blockIdx.x * blockDim.x + threadIdx.x;
    if (i < n4) {
        float4 v = src[i];
        ushort4 o;
        o.x = f32_to_bf16(v.x); o.y = f32_to_bf16(v.y);
        o.z = f32_to_bf16(v.z); o.w = f32_to_bf16(v.w);
        *(ushort4*)(dst + (size_t)i * 4) = o;
    }
}

// ---------------- gather first R tokens per batch, * SCALE, -> bf16 ----------------
__global__ __launch_bounds__(256)
void gather_q_kernel(const float* __restrict__ x, u16* __restrict__ xqp) {
    int i = blockIdx.x * blockDim.x + threadIdx.x;  // < 64*1536
    int m = i / Cc, c = i - m * Cc;
    int b = m >> 3, r = m & 7;
    xqp[i] = f32_to_bf16(x[((size_t)b * Nn + r) * Cc + c] * 0.125f);  // SCALE=hd^-0.5
}

// ---------------- m97-style GEMM: C[M,N] = A[M,K] * B[N,K]^T (+bias) ----------------
__device__ __forceinline__ void storeC(float* C, size_t i, float v) { C[i] = v; }
__device__ __forceinline__ void storeC(u16* C, size_t i, float v) { C[i] = f32_to_bf16(v); }

template <typename OutT>
__global__ __launch_bounds__(256)
void gemm_bt(const u16* __restrict__ A, const u16* __restrict__ B,
             OutT* __restrict__ C, const float* __restrict__ bias,
             int M, int N, int K, int M_valid)
{
    __shared__ u16 As[128 * 32];
    __shared__ u16 Bs[128 * 32];
    const int tid = threadIdx.x;
    const int m0 = blockIdx.y * 128;
    const int n0 = blockIdx.x * 128;
    const int wave = tid >> 6;
    const int lane = tid & 63;
    const int wm = (wave & 1) * 64;
    const int wn = (wave >> 1) * 64;
    const int fm = lane & 15;            // row within 16x16 frag
    const int ko = (lane >> 4) * 8;      // k offset within frag

    f32x4 acc[4][4] = {};

    // staging: 256 threads x 16B x 2 chunks = 8192B = 128x32 bf16 tile
    const int e0 = tid * 8;              // element offset, chunk 0
    const int e1 = tid * 8 + 2048;       // chunk 1
    const int r0 = e0 >> 5, c0 = e0 & 31;
    const int r1 = e1 >> 5, c1 = e1 & 31;
    const u16* Arow0 = A + (size_t)(m0 + r0) * K + c0;
    const u16* Arow1 = A + (size_t)(m0 + r1) * K + c1;
    const u16* Brow0 = B + (size_t)(n0 + r0) * K + c0;
    const u16* Brow1 = B + (size_t)(n0 + r1) * K + c1;

    for (int k0 = 0; k0 < K; k0 += 32) {
        __builtin_amdgcn_global_load_lds(
            (const __attribute__((address_space(1))) void*)(Arow0 + k0),
            (__attribute__((address_space(3))) void*)(As + e0), 16, 0, 0);
        __builtin_amdgcn_global_load_lds(
            (const __attribute__((address_space(1))) void*)(Arow1 + k0),
            (__attribute__((address_space(3))) void*)(As + e1), 16, 0, 0);
        __builtin_amdgcn_global_load_lds(
            (const __attribute__((address_space(1))) void*)(Brow0 + k0),
            (__attribute__((address_space(3))) void*)(Bs + e0), 16, 0, 0);
        __builtin_amdgcn_global_load_lds(
            (const __attribute__((address_space(1))) void*)(Brow1 + k0),
            (__attribute__((address_space(3))) void*)(Bs + e1), 16, 0, 0);
        __syncthreads();

        bf16x8 af[4], bfr[4];
        #pragma unroll
        for (int i = 0; i < 4; ++i)
            af[i] = *(const bf16x8*)&As[(wm + i * 16 + fm) * 32 + ko];
        #pragma unroll
        for (int j = 0; j < 4; ++j)
            bfr[j] = *(const bf16x8*)&Bs[(wn + j * 16 + fm) * 32 + ko];
        #pragma unroll
        for (int i = 0; i < 4; ++i)
            #pragma unroll
            for (int j = 0; j < 4; ++j)
                acc[i][j] = __builtin_amdgcn_mfma_f32_16x16x32_bf16(af[i], bfr[j], acc[i][j], 0, 0, 0);
        __syncthreads();
    }

    // C/D layout: col = lane&15, row = (lane>>4)*4 + reg  [guide m89, verified]
    const int col = lane & 15;
    const int rb = (lane >> 4) * 4;
    #pragma unroll
    for (int i = 0; i < 4; ++i) {
        #pragma unroll
        for (int j = 0; j < 4; ++j) {
            #pragma unroll
            for (int rg = 0; rg < 4; ++rg) {
                int m = m0 + wm + i * 16 + rb + rg;
                if (m < M_valid) {
                    int n = n0 + wn + j * 16 + col;
                    float v = acc[i][j][rg];
                    if (bias) v += bias[n];
                    storeC(C, (size_t)m * N + n, v);
                }
            }
        }
    }
}

// ---------------- split attention: grid (NCHUNK, B*H), 256 keys per block ----------------
// kv: bf16 [MKV, 3072]; cols 0..1535 = K proj, 1536..3071 = V proj
// qout: f32 [128,1536] rows (b*8+r)
// opart: f32 [192][NCHUNK][8][64]; mstat/lstat: f32 [192][NCHUNK][8]
__global__ __launch_bounds__(256)
void attn_part_kernel(const float* __restrict__ qout, const u16* __restrict__ kv,
                      const int* __restrict__ mask,
                      float* __restrict__ opart, float* __restrict__ mstat,
                      float* __restrict__ lstat)
{
    const int chunk = blockIdx.x;       // 0..15
    const int bh = blockIdx.y;          // 0..191
    const int b = bh / Hh, h = bh - b * Hh;
    const int tid = threadIdx.x;

    __shared__ u16  Vs[CK * HD];        // 32 KB
    __shared__ float Ps[RR][CK];        // 8 KB
    __shared__ float qs[RR * HD];       // 2 KB

    // ---- q tile to LDS ----
    for (int i = tid; i < RR * HD; i += 256)
        qs[i] = qout[(size_t)(b * RR + (i >> 6)) * Cc + h * HD + (i & 63)];
    __syncthreads();

    // ---- issue V-chunk DMA (overlaps with QK^T phase; drained by next barrier) ----
    {
        const u16* vsrc = kv + (size_t)(b * Nn + chunk * CK) * NKV + Cc + h * HD;
        const int vr = tid >> 3, vc = (tid & 7) * 8;
        #pragma unroll
        for (int i = 0; i < 8; ++i) {
            __builtin_amdgcn_global_load_lds(
                (const __attribute__((address_space(1))) void*)(vsrc + (size_t)(i * 32 + vr) * NKV + vc),
                (__attribute__((address_space(3))) void*)(Vs + i * 2048 + tid * 8), 16, 0, 0);
        }
    }

    // ---- phase A: thread = key; masked scores into Ps ----
    {
        const int j = chunk * CK + tid;
        float s[RR] = {0, 0, 0, 0, 0, 0, 0, 0};
        const u16* krow = kv + (size_t)(b * Nn + j) * NKV + h * HD;
        #pragma unroll
        for (int c = 0; c < 8; ++c) {
            uint4 kvec = *(const uint4*)(krow + c * 8);
            float kf0 = bflo(kvec.x), kf1 = bfhi(kvec.x);
            float kf2 = bflo(kvec.y), kf3 = bfhi(kvec.y);
            float kf4 = bflo(kvec.z), kf5 = bfhi(kvec.z);
            float kf6 = bflo(kvec.w), kf7 = bfhi(kvec.w);
            #pragma unroll
            for (int r = 0; r < RR; ++r) {
                const float4 qa = *(const float4*)&qs[r * HD + c * 8];
                const float4 qb = *(const float4*)&qs[r * HD + c * 8 + 4];
                s[r] += qa.x * kf0 + qa.y * kf1 + qa.z * kf2 + qa.w * kf3
                      + qb.x * kf4 + qb.y * kf5 + qb.z * kf6 + qb.w * kf7;
            }
        }
        #pragma unroll
        for (int r = 0; r < RR; ++r) {
            bool keep = (j < RR) ? (j == r)
                                 : (mask[(size_t)(b * RR + r) * (Nn - RR) + (j - RR)] != 0);
            Ps[r][tid] = keep ? s[r] : -INFINITY;
        }
    }
    __syncthreads();   // Ps visible; V DMA drained (vmcnt(0) before barrier)

    // ---- phase A2: per-r chunk max & exp-sum (8 groups of 32 lanes) ----
    {
        const int r = tid >> 5, g = tid & 31;
        float vals[CK / 32];
        float mx = -INFINITY;
        #pragma unroll
        for (int i = 0; i < CK / 32; ++i) {
            vals[i] = Ps[r][g + 32 * i];
            mx = fmaxf(mx, vals[i]);
        }
        #pragma unroll
        for (int m = 16; m >= 1; m >>= 1) mx = fmaxf(mx, __shfl_xor(mx, m));
        const float mfin = fmaxf(mx, -1e30f);   // avoid inf-inf if fully masked
        float sum = 0.f;
        #pragma unroll
        for (int i = 0; i < CK / 32; ++i) {
            float e = __expf(vals[i] - mfin);
            Ps[r][g + 32 * i] = e;
            sum += e;
        }
        #pragma unroll
        for (int m = 16; m >= 1; m >>= 1) sum += __shfl_xor(sum, m);
        if (g == 0) {
            size_t si = ((size_t)bh * NCHUNK + chunk) * RR + r;
            mstat[si] = mx;
            lstat[si] = sum;
        }
    }
    __syncthreads();   // Ps (now probs) visible to all

    // ---- phase B: o[r,d] = sum_k P[r,k] * V[k,d] from LDS ----
    {
        const int r = tid >> 5;
        const int d = (tid & 31) * 2;
        const float* pr = Ps[r];
        float a0 = 0.f, a1 = 0.f;
        #pragma unroll 8
        for (int k = 0; k < CK; ++k) {
            float p = pr[k];                          // broadcast
            u32 vv = *(const u32*)&Vs[k * HD + d];    // 32-bank striped, 2 lanes/addr
            a0 += p * bflo(vv);
            a1 += p * bfhi(vv);
        }
        size_t po = ((size_t)bh * NCHUNK + chunk) * (RR * HD) + r * HD + d;
        opart[po]     = a0;
        opart[po + 1] = a1;
    }
}

// ---------------- combine partials -> bf16 attention output ----------------
__global__ __launch_bounds__(256)
void attn_combine_kernel(const float* __restrict__ opart, const float* __restrict__ mstat,
                         const float* __restrict__ lstat, u16* __restrict__ aob)
{
    int idx = blockIdx.x * 256 + threadIdx.x;   // < 64*1536
    int row = idx / Cc, col = idx - row * Cc;   // row = b*8+r, col = h*64+d
    int b = row >> 3, r = row & 7;
    int h = col >> 6, d = col & 63;
    int bh = b * Hh + h;
    float M = -INFINITY;
    #pragma unroll
    for (int c = 0; c < NCHUNK; ++c)
        M = fmaxf(M, mstat[((size_t)bh * NCHUNK + c) * RR + r]);
    float L = 0.f, O = 0.f;
    #pragma unroll
    for (int c = 0; c < NCHUNK; ++c) {
        size_t si = ((size_t)bh * NCHUNK + c) * RR + r;
        float w = __expf(mstat[si] - M);
        L += w * lstat[si];
        O += w * opart[((size_t)bh * NCHUNK + c) * (RR * HD) + r * HD + d];
    }
    aob[(size_t)row * Cc + col] = f32_to_bf16(O / L);
}

// ---------------- launch ----------------
extern "C" void kernel_launch(void* const* d_in, const int* in_sizes, int n_in,
                              void* d_out, int out_size, void* d_ws, size_t ws_size,
                              hipStream_t stream)
{
    const float* x    = (const float*)d_in[0];
    const int*   mask = (const int*)d_in[1];
    const float* Wq   = (const float*)d_in[2];
    const float* Wk   = (const float*)d_in[3];
    const float* Wv   = (const float*)d_in[4];
    const float* Wp   = (const float*)d_in[5];
    const float* bp   = (const float*)d_in[6];
    // d_in[7] = repeats (=8, hardcoded as RR)

    char* ws = (char*)d_ws;
    // workspace layout (bytes), ~322.5 MB total
    u16*   xb     = (u16*)(ws);                       // 100,663,296  x bf16 [32768,1536]
    u16*   wkvb   = (u16*)(ws + 100663296);           //   9,437,184  [Wk;Wv] bf16 [3072,1536]
    u16*   wqb    = (u16*)(ws + 110100480);           //   4,718,592  Wq bf16
    u16*   wpb    = (u16*)(ws + 114819072);           //   4,718,592  Wp bf16
    u16*   kvb    = (u16*)(ws + 119537664);           // 201,326,592  kv bf16 [32768,3072]
    u16*   xqp    = (u16*)(ws + 320864256);           //     393,216  q input padded [128,1536] bf16
    float* qout   = (float*)(ws + 321257472);         //     786,432  q proj f32 [128,1536]
    u16*   aob    = (u16*)(ws + 322043904);           //     393,216  attn out padded [128,1536] bf16
    // partials alias xb (dead after KV GEMM): 6.29 MB + 2*96 KB
    float* opart  = (float*)(ws);                     // 192*16*8*64 f32 = 6,291,456 B
    float* mstat  = (float*)(ws + 6291456);           // 98,304 B
    float* lstat  = (float*)(ws + 6389760);           // 98,304 B

    // casts (x: 12.58M quads; W: 589824 quads each)
    cast4_f32_bf16<<<49152, 256, 0, stream>>>((const float4*)x, xb, 12582912);
    cast4_f32_bf16<<<2304, 256, 0, stream>>>((const float4*)Wk, wkvb, 589824);
    cast4_f32_bf16<<<2304, 256, 0, stream>>>((const float4*)Wv, wkvb + 2359296, 589824);
    cast4_f32_bf16<<<2304, 256, 0, stream>>>((const float4*)Wq, wqb, 589824);
    cast4_f32_bf16<<<2304, 256, 0, stream>>>((const float4*)Wp, wpb, 589824);

    // zero pad rows of the two M=128-padded GEMM inputs
    hipMemsetAsync(xqp, 0, 128 * Cc * sizeof(u16), stream);
    hipMemsetAsync(aob, 0, 128 * Cc * sizeof(u16), stream);

    gather_q_kernel<<<384, 256, 0, stream>>>(x, xqp);

    // q projection: [128,1536] = xqp @ Wq^T   (scale already folded into xqp)
    gemm_bt<float><<<dim3(12, 1), 256, 0, stream>>>(xqp, wqb, qout, nullptr, 128, Cc, Cc, 128);

    // fused K+V projection: [32768,3072] = xb @ [Wk;Wv]^T
    gemm_bt<u16><<<dim3(NKV / 128, MKV / 128), 256, 0, stream>>>(xb, wkvb, kvb, nullptr,
                                                                 MKV, NKV, Cc, MKV);

    // split attention (3072 blocks) + combine
    attn_part_kernel<<<dim3(NCHUNK, Bb * Hh), 256, 0, stream>>>(qout, kvb, mask,
                                                                opart, mstat, lstat);
    attn_combine_kernel<<<384, 256, 0, stream>>>(opart, mstat, lstat, aob);

    // output projection: d_out[64,1536] = aob @ Wp^T + bp
    gemm_bt<float><<<dim3(12, 1), 256, 0, stream>>>(aob, wpb, (float*)d_out, bp, 128, Cc, Cc, 64);
}

// Round 3
// 855.983 us; speedup vs baseline: 1.7903x; 1.1993x over previous
//
#include <hip/hip_runtime.h>
#include <hip/hip_bf16.h>
#include <math.h>

// Problem constants (AttentionPool): B=8, N=4096, C=1536, H=24, hd=64, R=8
#define Bb 8
#define Nn 4096
#define Cc 1536
#define Hh 24
#define HD 64
#define RR 8
#define MKV (Bb * Nn)        // 32768 rows for K/V GEMM
#define NKV (2 * Cc)         // 3072 cols (K and V fused)
#define NCHUNK 16            // key chunks for split attention
#define CK 256               // keys per chunk

typedef unsigned short u16;
typedef unsigned int u32;

typedef __attribute__((ext_vector_type(8))) short bf16x8;
typedef __attribute__((ext_vector_type(4))) float f32x4;

__device__ __forceinline__ u16 f32_to_bf16(float f) {
    union { float f; u32 u; } v; v.f = f;
    u32 r = v.u + 0x7fffu + ((v.u >> 16) & 1u);  // RNE
    return (u16)(r >> 16);
}
__device__ __forceinline__ float bflo(u32 p) {
    union { u32 u; float f; } v; v.u = p << 16; return v.f;
}
__device__ __forceinline__ float bfhi(u32 p) {
    union { u32 u; float f; } v; v.u = p & 0xffff0000u; return v.f;
}
__device__ __forceinline__ ushort4 cvt4(float4 v, float s) {
    ushort4 o;
    o.x = f32_to_bf16(v.x * s); o.y = f32_to_bf16(v.y * s);
    o.z = f32_to_bf16(v.z * s); o.w = f32_to_bf16(v.w * s);
    return o;
}

// ---------------- fused prep: casts + q gather + zero fills, one dispatch ----------------
// sections: [0,49152) x-cast+gather | [49152,58368) 4 weights | [58368,58464) zero xqp hi
//           [58464,58656) zero aob | [58656,58752) zero d_out
__global__ __launch_bounds__(256)
void prep_kernel(const float* __restrict__ x,
                 const float* __restrict__ Wk, const float* __restrict__ Wv,
                 const float* __restrict__ Wq, const float* __restrict__ Wp,
                 u16* __restrict__ xb, u16* __restrict__ wkvb,
                 u16* __restrict__ wqb, u16* __restrict__ wpb,
                 u16* __restrict__ xqp, u16* __restrict__ aob,
                 float* __restrict__ dout)
{
    const int blk = blockIdx.x, tid = threadIdx.x;
    if (blk < 49152) {
        int i = blk * 256 + tid;                 // quad index < 12582912
        float4 v = ((const float4*)x)[i];
        ((ushort4*)xb)[i] = cvt4(v, 1.0f);
        int row = i / 384;                       // 384 quads per 1536-row
        int n = row & (Nn - 1);
        if (n < RR) {                            // q gather, SCALE=0.125 folded (exact)
            int b = row >> 12;
            int cq = i - row * 384;
            ((ushort4*)xqp)[(size_t)(b * RR + n) * 384 + cq] = cvt4(v, 0.125f);
        }
    } else if (blk < 58368) {
        int t = blk - 49152;
        int w = t / 2304;
        int i = (t - w * 2304) * 256 + tid;      // < 589824 quads
        const float4* src = (w == 0) ? (const float4*)Wk : (w == 1) ? (const float4*)Wv
                          : (w == 2) ? (const float4*)Wq : (const float4*)Wp;
        u16* dst = (w == 0) ? wkvb : (w == 1) ? wkvb + 2359296 : (w == 2) ? wqb : wpb;
        ((ushort4*)dst)[i] = cvt4(src[i], 1.0f);
    } else if (blk < 58464) {                    // zero xqp rows 64..127
        int i = (blk - 58368) * 256 + tid;
        ushort4 z = {0, 0, 0, 0};
        ((ushort4*)(xqp + 64 * Cc))[i] = z;
    } else if (blk < 58656) {                    // zero aob (all 128 rows)
        int i = (blk - 58464) * 256 + tid;
        ushort4 z = {0, 0, 0, 0};
        ((ushort4*)aob)[i] = z;
    } else {                                     // zero d_out (for split-K atomics)
        int i = (blk - 58656) * 256 + tid;
        float4 z = {0.f, 0.f, 0.f, 0.f};
        ((float4*)dout)[i] = z;
    }
}

// ---------------- GEMM body: 128x128 tile, BK=64, XOR-swizzled LDS ----------------
// C[M,N] = A[M,K] * B[N,K]^T.  LDS row = 64 elems (128 B); chunk = 8 elems (16 B);
// chunk c of row r stored at c ^ (r&7)  -> fragment reads are 2-way (free) per bank-quad.
// OUT: 0 = f32 store, 1 = bf16 store, 2 = f32 atomicAdd (split-K)
template <int OUT>
__device__ __forceinline__ void gemm_body64(
    const u16* __restrict__ A, const u16* __restrict__ B, void* __restrict__ Cv,
    const float* __restrict__ bias, int M_valid, int N, int K,
    int m0, int n0, int kbeg, int kend, u16* As, u16* Bs)
{
    const int tid = threadIdx.x;
    const int wave = tid >> 6, lane = tid & 63;
    const int wm = (wave & 1) * 64, wn = (wave >> 1) * 64;
    const int fm = lane & 15;
    const int kq = lane >> 4;            // 0..3

    f32x4 acc[4][4] = {};

    // staging: LDS slot e = tid*8 + off*2048 elems; r=e>>6, c'=(e>>3)&7; src chunk c'^(r&7)
    const u16* aptr[4]; const u16* bptr[4]; int ldsoff[4];
    #pragma unroll
    for (int off = 0; off < 4; ++off) {
        int e = tid * 8 + off * 2048;
        int r = e >> 6, cp = (e >> 3) & 7;
        int csrc = cp ^ (r & 7);
        aptr[off] = A + (size_t)(m0 + r) * K + csrc * 8;
        bptr[off] = B + (size_t)(n0 + r) * K + csrc * 8;
        ldsoff[off] = e;
    }

    for (int k0 = kbeg; k0 < kend; k0 += 64) {
        #pragma unroll
        for (int off = 0; off < 4; ++off)
            __builtin_amdgcn_global_load_lds(
                (const __attribute__((address_space(1))) void*)(aptr[off] + k0),
                (__attribute__((address_space(3))) void*)(As + ldsoff[off]), 16, 0, 0);
        #pragma unroll
        for (int off = 0; off < 4; ++off)
            __builtin_amdgcn_global_load_lds(
                (const __attribute__((address_space(1))) void*)(bptr[off] + k0),
                (__attribute__((address_space(3))) void*)(Bs + ldsoff[off]), 16, 0, 0);
        __syncthreads();

        #pragma unroll
        for (int ks = 0; ks < 2; ++ks) {
            bf16x8 af[4], bfr[4];
            #pragma unroll
            for (int i = 0; i < 4; ++i) {
                int r = wm + i * 16 + fm;
                int c = ks * 4 + kq;
                af[i] = *(const bf16x8*)&As[r * 64 + ((c ^ (r & 7)) << 3)];
            }
            #pragma unroll
            for (int j = 0; j < 4; ++j) {
                int r = wn + j * 16 + fm;
                int c = ks * 4 + kq;
                bfr[j] = *(const bf16x8*)&Bs[r * 64 + ((c ^ (r & 7)) << 3)];
            }
            #pragma unroll
            for (int i = 0; i < 4; ++i)
                #pragma unroll
                for (int j = 0; j < 4; ++j)
                    acc[i][j] = __builtin_amdgcn_mfma_f32_16x16x32_bf16(af[i], bfr[j], acc[i][j], 0, 0, 0);
        }
        __syncthreads();
    }

    // C/D layout: col = lane&15, row = (lane>>4)*4 + reg  [m89, verified]
    const int col = lane & 15, rb = (lane >> 4) * 4;
    #pragma unroll
    for (int i = 0; i < 4; ++i)
        #pragma unroll
        for (int j = 0; j < 4; ++j)
            #pragma unroll
            for (int rg = 0; rg < 4; ++rg) {
                int m = m0 + wm + i * 16 + rb + rg;
                if (m < M_valid) {
                    int n = n0 + wn + j * 16 + col;
                    float v = acc[i][j][rg];
                    if (bias) v += bias[n];
                    size_t idx = (size_t)m * N + n;
                    if (OUT == 0)       ((float*)Cv)[idx] = v;
                    else if (OUT == 1)  ((u16*)Cv)[idx] = f32_to_bf16(v);
                    else                atomicAdd((float*)Cv + idx, v);
                }
            }
}

// ---------------- merged dispatch: blocks 0..11 = q proj; 12..6155 = KV proj ----------------
// KV decode is XCD-aware: class g = u&7 owns m-tiles [g*32, g*32+32), n fastest
// (A row-tile stays in that XCD's L2 across its 24-block n-sweep; B lives in L3).
__global__ __launch_bounds__(256, 3)
void gemm_main(const u16* __restrict__ xqp, const u16* __restrict__ wqb,
               float* __restrict__ qout,
               const u16* __restrict__ xb, const u16* __restrict__ wkvb,
               u16* __restrict__ kvb)
{
    __shared__ u16 As[128 * 64];
    __shared__ u16 Bs[128 * 64];
    const int blk = blockIdx.x;
    if (blk < 12) {
        gemm_body64<0>(xqp, wqb, qout, nullptr, 64, Cc, Cc, 0, blk * 128, 0, Cc, As, Bs);
    } else {
        int u = blk - 12;
        int g = u & 7, s = u >> 3;               // 768 blocks per class
        int mb = g * 32 + s / 24, nb = s % 24;
        gemm_body64<1>(xb, wkvb, kvb, nullptr, MKV, NKV, Cc, mb * 128, nb * 128, 0, Cc, As, Bs);
    }
}

// ---------------- output projection, split-K x4 with f32 atomics ----------------
__global__ __launch_bounds__(256, 3)
void gemm_out(const u16* __restrict__ aob, const u16* __restrict__ wpb,
              float* __restrict__ out, const float* __restrict__ bp)
{
    __shared__ u16 As[128 * 64];
    __shared__ u16 Bs[128 * 64];
    const int nb = blockIdx.x;                   // 0..11
    const int z = blockIdx.y;                    // 0..3
    gemm_body64<2>(aob, wpb, out, (z == 0) ? bp : nullptr,
                   64, Cc, Cc, 0, nb * 128, z * 384, (z + 1) * 384, As, Bs);
}

// ---------------- split attention: grid (NCHUNK, B*H), 256 keys per block ----------------
__global__ __launch_bounds__(256)
void attn_part_kernel(const float* __restrict__ qout, const u16* __restrict__ kv,
                      const int* __restrict__ mask,
                      float* __restrict__ opart, float* __restrict__ mstat,
                      float* __restrict__ lstat)
{
    const int chunk = blockIdx.x;       // 0..15
    const int bh = blockIdx.y;          // 0..191
    const int b = bh / Hh, h = bh - b * Hh;
    const int tid = threadIdx.x;

    __shared__ u16  Vs[CK * HD];        // 32 KB
    __shared__ float Ps[RR][CK];        // 8 KB
    __shared__ float qs[RR * HD];       // 2 KB

    for (int i = tid; i < RR * HD; i += 256)
        qs[i] = qout[(size_t)(b * RR + (i >> 6)) * Cc + h * HD + (i & 63)];
    __syncthreads();

    // V-chunk DMA (overlaps QK^T; drained by the next barrier)
    {
        const u16* vsrc = kv + (size_t)(b * Nn + chunk * CK) * NKV + Cc + h * HD;
        const int vr = tid >> 3, vc = (tid & 7) * 8;
        #pragma unroll
        for (int i = 0; i < 8; ++i) {
            __builtin_amdgcn_global_load_lds(
                (const __attribute__((address_space(1))) void*)(vsrc + (size_t)(i * 32 + vr) * NKV + vc),
                (__attribute__((address_space(3))) void*)(Vs + i * 2048 + tid * 8), 16, 0, 0);
        }
    }

    // phase A: thread = key; masked scores
    {
        const int j = chunk * CK + tid;
        float s[RR] = {0, 0, 0, 0, 0, 0, 0, 0};
        const u16* krow = kv + (size_t)(b * Nn + j) * NKV + h * HD;
        #pragma unroll
        for (int c = 0; c < 8; ++c) {
            uint4 kvec = *(const uint4*)(krow + c * 8);
            float kf0 = bflo(kvec.x), kf1 = bfhi(kvec.x);
            float kf2 = bflo(kvec.y), kf3 = bfhi(kvec.y);
            float kf4 = bflo(kvec.z), kf5 = bfhi(kvec.z);
            float kf6 = bflo(kvec.w), kf7 = bfhi(kvec.w);
            #pragma unroll
            for (int r = 0; r < RR; ++r) {
                const float4 qa = *(const float4*)&qs[r * HD + c * 8];
                const float4 qb = *(const float4*)&qs[r * HD + c * 8 + 4];
                s[r] += qa.x * kf0 + qa.y * kf1 + qa.z * kf2 + qa.w * kf3
                      + qb.x * kf4 + qb.y * kf5 + qb.z * kf6 + qb.w * kf7;
            }
        }
        #pragma unroll
        for (int r = 0; r < RR; ++r) {
            bool keep = (j < RR) ? (j == r)
                                 : (mask[(size_t)(b * RR + r) * (Nn - RR) + (j - RR)] != 0);
            Ps[r][tid] = keep ? s[r] : -INFINITY;
        }
    }
    __syncthreads();

    // phase A2: per-row chunk max & exp-sum
    {
        const int r = tid >> 5, g = tid & 31;
        float vals[CK / 32];
        float mx = -INFINITY;
        #pragma unroll
        for (int i = 0; i < CK / 32; ++i) {
            vals[i] = Ps[r][g + 32 * i];
            mx = fmaxf(mx, vals[i]);
        }
        #pragma unroll
        for (int m = 16; m >= 1; m >>= 1) mx = fmaxf(mx, __shfl_xor(mx, m));
        const float mfin = fmaxf(mx, -1e30f);
        float sum = 0.f;
        #pragma unroll
        for (int i = 0; i < CK / 32; ++i) {
            float e = __expf(vals[i] - mfin);
            Ps[r][g + 32 * i] = e;
            sum += e;
        }
        #pragma unroll
        for (int m = 16; m >= 1; m >>= 1) sum += __shfl_xor(sum, m);
        if (g == 0) {
            size_t si = ((size_t)bh * NCHUNK + chunk) * RR + r;
            mstat[si] = mx;
            lstat[si] = sum;
        }
    }
    __syncthreads();

    // phase B: o[r,d] = sum_k P[r,k] * V[k,d] from LDS
    {
        const int r = tid >> 5;
        const int d = (tid & 31) * 2;
        const float* pr = Ps[r];
        float a0 = 0.f, a1 = 0.f;
        #pragma unroll 8
        for (int k = 0; k < CK; ++k) {
            float p = pr[k];
            u32 vv = *(const u32*)&Vs[k * HD + d];
            a0 += p * bflo(vv);
            a1 += p * bfhi(vv);
        }
        size_t po = ((size_t)bh * NCHUNK + chunk) * (RR * HD) + r * HD + d;
        opart[po]     = a0;
        opart[po + 1] = a1;
    }
}

// ---------------- combine partials -> bf16 attention output ----------------
__global__ __launch_bounds__(256)
void attn_combine_kernel(const float* __restrict__ opart, const float* __restrict__ mstat,
                         const float* __restrict__ lstat, u16* __restrict__ aob)
{
    int idx = blockIdx.x * 256 + threadIdx.x;   // < 64*1536
    int row = idx / Cc, col = idx - row * Cc;
    int b = row >> 3, r = row & 7;
    int h = col >> 6, d = col & 63;
    int bh = b * Hh + h;
    float M = -INFINITY;
    #pragma unroll
    for (int c = 0; c < NCHUNK; ++c)
        M = fmaxf(M, mstat[((size_t)bh * NCHUNK + c) * RR + r]);
    float L = 0.f, O = 0.f;
    #pragma unroll
    for (int c = 0; c < NCHUNK; ++c) {
        size_t si = ((size_t)bh * NCHUNK + c) * RR + r;
        float w = __expf(mstat[si] - M);
        L += w * lstat[si];
        O += w * opart[((size_t)bh * NCHUNK + c) * (RR * HD) + r * HD + d];
    }
    aob[(size_t)row * Cc + col] = f32_to_bf16(O / L);
}

// ---------------- launch ----------------
extern "C" void kernel_launch(void* const* d_in, const int* in_sizes, int n_in,
                              void* d_out, int out_size, void* d_ws, size_t ws_size,
                              hipStream_t stream)
{
    const float* x    = (const float*)d_in[0];
    const int*   mask = (const int*)d_in[1];
    const float* Wq   = (const float*)d_in[2];
    const float* Wk   = (const float*)d_in[3];
    const float* Wv   = (const float*)d_in[4];
    const float* Wp   = (const float*)d_in[5];
    const float* bp   = (const float*)d_in[6];

    char* ws = (char*)d_ws;
    u16*   xb     = (u16*)(ws);                       // 100,663,296  x bf16 [32768,1536]
    u16*   wkvb   = (u16*)(ws + 100663296);           //   9,437,184  [Wk;Wv] bf16 [3072,1536]
    u16*   wqb    = (u16*)(ws + 110100480);           //   4,718,592  Wq bf16
    u16*   wpb    = (u16*)(ws + 114819072);           //   4,718,592  Wp bf16
    u16*   kvb    = (u16*)(ws + 119537664);           // 201,326,592  kv bf16 [32768,3072]
    u16*   xqp    = (u16*)(ws + 320864256);           //     393,216  q input padded [128,1536]
    float* qout   = (float*)(ws + 321257472);         //     786,432  q proj f32 [128,1536]
    u16*   aob    = (u16*)(ws + 322043904);           //     393,216  attn out padded [128,1536]
    // partials alias xb (dead after KV GEMM)
    float* opart  = (float*)(ws);                     // 6,291,456 B
    float* mstat  = (float*)(ws + 6291456);           // 98,304 B
    float* lstat  = (float*)(ws + 6389760);           // 98,304 B

    // 1: all casts + q gather + zero fills
    prep_kernel<<<58752, 256, 0, stream>>>(x, Wk, Wv, Wq, Wp, xb, wkvb, wqb, wpb,
                                           xqp, aob, (float*)d_out);
    // 2: q proj (blocks 0..11) + fused K/V proj (blocks 12..6155)
    gemm_main<<<6156, 256, 0, stream>>>(xqp, wqb, qout, xb, wkvb, kvb);
    // 3: split attention
    attn_part_kernel<<<dim3(NCHUNK, Bb * Hh), 256, 0, stream>>>(qout, kvb, mask,
                                                                opart, mstat, lstat);
    // 4: combine
    attn_combine_kernel<<<384, 256, 0, stream>>>(opart, mstat, lstat, aob);
    // 5: output projection, split-K atomics (d_out zeroed by prep)
    gemm_out<<<dim3(12, 4), 256, 0, stream>>>(aob, wpb, (float*)d_out, bp);
}